// Round 3
// baseline (761.248 us; speedup 1.0000x reference)
//
#include <hip/hip_runtime.h>
#include <cstdint>

#define D_MODEL 768
#define NHEAD 12
#define HDIM 64
#define LSEQ 257
#define NBATCH 64
#define MROWS (LSEQ*NBATCH)   // 16448

typedef unsigned short u16;
typedef __attribute__((ext_vector_type(8))) short short8;
typedef __attribute__((ext_vector_type(4))) float floatx4;

__device__ __forceinline__ float b2f(u16 u){ return __uint_as_float(((unsigned)u)<<16); }
__device__ __forceinline__ u16 f2bf(float f){
  unsigned x = __float_as_uint(f);
  return (u16)((x + 0x7fffu + ((x>>16)&1u)) >> 16);
}

// ---------------- LayerNorm: one wave per row of 768; fp32 gains ----------------
template<typename TIN>
__global__ __launch_bounds__(256) void ln_kernel(const TIN* __restrict__ x,
    const float* __restrict__ g, const float* __restrict__ b,
    u16* __restrict__ out, int rows)
{
  int wv = threadIdx.x >> 6, lane = threadIdx.x & 63;
  int row = blockIdx.x*4 + wv;
  if (row >= rows) return;
  const TIN* xr = x + (size_t)row*D_MODEL;
  float v[12]; float s = 0.f, s2 = 0.f;
#pragma unroll
  for (int i=0;i<12;++i){
    float f;
    if constexpr (sizeof(TIN)==2) f = b2f(((const u16*)xr)[lane + i*64]);
    else                          f = ((const float*)xr)[lane + i*64];
    v[i]=f; s+=f; s2+=f*f;
  }
#pragma unroll
  for (int o=32;o>0;o>>=1){ s += __shfl_xor(s,o,64); s2 += __shfl_xor(s2,o,64); }
  float mu = s*(1.f/768.f);
  float var = fmaxf(s2*(1.f/768.f) - mu*mu, 0.f);
  float rs = rsqrtf(var + 1e-5f);
  u16* orow = out + (size_t)row*D_MODEL;
#pragma unroll
  for (int i=0;i<12;++i){
    int c = lane + i*64;
    orow[c] = f2bf((v[i]-mu)*rs*g[c] + b[c]);
  }
}

// ---------------- GEMM: C[M,N] = A[M,K](bf16) * B[N,K]^T(fp32->bf16) + bias(fp32) ----------------
// EPI 0: C=bf16(acc+bias)                          (qkv, internal)
// EPI 1: C=bf16(resid_f32 + acc+bias)              (out_proj + residual(x fp32) -> x2 bf16 internal)
// EPI 2: y=acc+bias; C=f32(resid_bf16 + y*sigmoid(1.702y))  (fc+quickgelu+residual -> FINAL fp32 out)
#define BM 128
#define BN 128
#define BKK 32
#define LDSW 40   // 80B stride: 16B-aligned, bank period 8

template<int EPI>
__global__ __launch_bounds__(256,2) void gemm_bt(
    const u16* __restrict__ A, const float* __restrict__ B,
    const float* __restrict__ bias, void* __restrict__ Cout,
    const void* __restrict__ resid, int M, int N, int K)
{
  __shared__ u16 sA[BM*LDSW];
  __shared__ u16 sB[BN*LDSW];
  const int m0 = blockIdx.x * BM, n0 = blockIdx.y * BN;
  const int tid = threadIdx.x;
  const int lane = tid & 63, w = tid >> 6;
  const int wm = (w>>1)*64, wn = (w&1)*64;
  const int l16 = lane & 15, quad = lane >> 4;
  floatx4 acc[4][4];
#pragma unroll
  for (int i=0;i<4;++i)
#pragma unroll
    for (int j=0;j<4;++j) acc[i][j] = (floatx4){0.f,0.f,0.f,0.f};

  for (int k0=0;k0<K;k0+=BKK) {
    __syncthreads();
#pragma unroll
    for (int i=0;i<2;++i) {
      int idx = (tid + i*256)*8;
      int row = idx >> 5, col = idx & 31;
      uint4 va = {0u,0u,0u,0u};
      if (m0 + row < M) va = *(const uint4*)(A + (size_t)(m0+row)*K + k0 + col);
      *(uint4*)(sA + row*LDSW + col) = va;
      u16 tmp[8];
      if (n0 + row < N) {
        const float* bp = B + (size_t)(n0+row)*K + k0 + col;
        float4 f0 = *(const float4*)bp;
        float4 f1 = *(const float4*)(bp+4);
        tmp[0]=f2bf(f0.x); tmp[1]=f2bf(f0.y); tmp[2]=f2bf(f0.z); tmp[3]=f2bf(f0.w);
        tmp[4]=f2bf(f1.x); tmp[5]=f2bf(f1.y); tmp[6]=f2bf(f1.z); tmp[7]=f2bf(f1.w);
      } else {
#pragma unroll
        for (int t=0;t<8;++t) tmp[t]=0;
      }
      *(uint4*)(sB + row*LDSW + col) = *(const uint4*)tmp;
    }
    __syncthreads();
    short8 af[4], bfr[4];
#pragma unroll
    for (int t=0;t<4;++t) af[t]  = *(const short8*)(sA + (wm + t*16 + l16)*LDSW + quad*8);
#pragma unroll
    for (int t=0;t<4;++t) bfr[t] = *(const short8*)(sB + (wn + t*16 + l16)*LDSW + quad*8);
#pragma unroll
    for (int mt=0;mt<4;++mt)
#pragma unroll
      for (int nt=0;nt<4;++nt)
        acc[mt][nt] = __builtin_amdgcn_mfma_f32_16x16x32_bf16(af[mt], bfr[nt], acc[mt][nt], 0,0,0);
  }
#pragma unroll
  for (int mt=0;mt<4;++mt)
#pragma unroll
    for (int nt=0;nt<4;++nt) {
      int col = n0 + wn + nt*16 + l16;
      if (col >= N) continue;
      float bia = bias[col];
      int rowb = m0 + wm + mt*16 + quad*4;
#pragma unroll
      for (int r=0;r<4;++r) {
        int row = rowb + r;
        if (row >= M) continue;
        float vacc = acc[mt][nt][r] + bia;
        size_t off = (size_t)row*N + col;
        if (EPI==0) {
          ((u16*)Cout)[off] = f2bf(vacc);
        } else if (EPI==1) {
          ((u16*)Cout)[off] = f2bf(((const float*)resid)[off] + vacc);
        } else {
          float gl = vacc / (1.f + __expf(-1.702f*vacc));
          ((float*)Cout)[off] = b2f(((const u16*)resid)[off]) + gl;
        }
      }
    }
}

// ---------------- Fused attention: per (n,h) pair x 64-row Q tile ----------------
__global__ __launch_bounds__(256,2) void attn_kernel(
    const u16* __restrict__ qkv, float* __restrict__ wout, u16* __restrict__ attn)
{
  __shared__ __align__(16) u16 smem[29696];  // 59392 B
  u16* sQ  = smem;               // [64][72]
  u16* sK  = smem + 64*72;       // [272][72]
  u16* sP  = smem;               // [64][296]
  u16* sVt = smem + 64*296;      // [64][168]
  const int p = blockIdx.x;      // n*12 + h
  const int n = p / NHEAD, h = p % NHEAD;
  const int l0 = blockIdx.y * 64;
  const int tid = threadIdx.x, lane = tid & 63, w = tid >> 6;
  const int l16 = lane & 15, quad = lane >> 4;

  for (int i = tid; i < 64*8; i += 256) {
    int lr = i >> 3, c8 = (i & 7)*8;
    uint4 v = {0u,0u,0u,0u};
    int gl = l0 + lr;
    if (gl < LSEQ) v = *(const uint4*)(qkv + ((size_t)gl*NBATCH + n)*2304 + h*HDIM + c8);
    *(uint4*)(sQ + lr*72 + c8) = v;
  }
  for (int i = tid; i < 272*8; i += 256) {
    int kr = i >> 3, c8 = (i & 7)*8;
    uint4 v = {0u,0u,0u,0u};
    if (kr < LSEQ) v = *(const uint4*)(qkv + ((size_t)kr*NBATCH + n)*2304 + 768 + h*HDIM + c8);
    *(uint4*)(sK + kr*72 + c8) = v;
  }
  __syncthreads();

  floatx4 acc[17];
#pragma unroll
  for (int t=0;t<17;++t) acc[t] = (floatx4){0.f,0.f,0.f,0.f};
#pragma unroll
  for (int ks=0;ks<2;++ks) {
    short8 aq = *(const short8*)(sQ + (w*16 + l16)*72 + ks*32 + quad*8);
#pragma unroll
    for (int nt=0;nt<17;++nt) {
      short8 bk = *(const short8*)(sK + (nt*16 + l16)*72 + ks*32 + quad*8);
      acc[nt] = __builtin_amdgcn_mfma_f32_16x16x32_bf16(aq, bk, acc[nt], 0,0,0);
    }
  }
  __syncthreads();  // all sQ/sK reads complete before sP overwrites

#pragma unroll
  for (int r=0;r<4;++r) {
    float mx = -3.0e38f;
#pragma unroll
    for (int nt=0;nt<17;++nt) {
      int col = nt*16 + l16;
      float v = (col < LSEQ) ? acc[nt][r]*0.125f : -3.0e38f;
      acc[nt][r] = v;
      mx = fmaxf(mx, v);
    }
#pragma unroll
    for (int o=1;o<16;o<<=1) mx = fmaxf(mx, __shfl_xor(mx,o,64));
    float sum = 0.f;
#pragma unroll
    for (int nt=0;nt<17;++nt) {
      float e = __expf(acc[nt][r]-mx);
      acc[nt][r] = e; sum += e;
    }
#pragma unroll
    for (int o=1;o<16;o<<=1) sum += __shfl_xor(sum,o,64);
    float inv = 1.f/sum;
#pragma unroll
    for (int nt=0;nt<17;++nt) acc[nt][r] *= inv;
  }

  size_t wbase = (size_t)p * LSEQ * LSEQ;
#pragma unroll
  for (int r=0;r<4;++r) {
    int lr = w*16 + quad*4 + r;
    int gl = l0 + lr;
#pragma unroll
    for (int nt=0;nt<17;++nt) {
      int col = nt*16 + l16;
      sP[lr*296 + col] = f2bf(acc[nt][r]);
      if (gl < LSEQ && col < LSEQ) wout[wbase + (size_t)gl*LSEQ + col] = acc[nt][r];
    }
  }
  for (int i = tid; i < 64*16; i += 256) {
    int lr = i >> 4, c = 272 + (i & 15);
    sP[lr*296 + c] = 0;
  }
  __syncthreads();

  floatx4 acc2[4];
#pragma unroll
  for (int t=0;t<4;++t) acc2[t] = (floatx4){0.f,0.f,0.f,0.f};
  for (int c=0;c<2;++c) {
    if (c) __syncthreads();
    int mbase = c*160;
    int msz = c ? 128 : 160;
    for (int ml = tid; ml < msz; ml += 256) {
      int m = mbase + ml;
      if (m < LSEQ) {
        const u16* vr = qkv + ((size_t)m*NBATCH + n)*2304 + 1536 + h*HDIM;
#pragma unroll
        for (int d=0; d<64; ++d) sVt[d*168 + ml] = vr[d];
      } else {
#pragma unroll
        for (int d=0; d<64; ++d) sVt[d*168 + ml] = 0;
      }
    }
    __syncthreads();
    int nks = c ? 4 : 5;
    for (int ksl=0; ksl<nks; ++ksl) {
      short8 ap = *(const short8*)(sP + (w*16 + l16)*296 + mbase + ksl*32 + quad*8);
#pragma unroll
      for (int nt=0;nt<4;++nt) {
        short8 bv = *(const short8*)(sVt + (nt*16 + l16)*168 + ksl*32 + quad*8);
        acc2[nt] = __builtin_amdgcn_mfma_f32_16x16x32_bf16(ap, bv, acc2[nt], 0,0,0);
      }
    }
  }
#pragma unroll
  for (int nt=0;nt<4;++nt)
#pragma unroll
    for (int r=0;r<4;++r) {
      int lr = w*16 + quad*4 + r;
      int gl = l0 + lr;
      if (gl < LSEQ) {
        int d = nt*16 + l16;
        attn[((size_t)gl*NBATCH + n)*768 + h*HDIM + d] = f2bf(acc2[nt][r]);
      }
    }
}

extern "C" void kernel_launch(void* const* d_in, const int* in_sizes, int n_in,
                              void* d_out, int out_size, void* d_ws, size_t ws_size,
                              hipStream_t stream)
{
  (void)in_sizes; (void)n_in; (void)out_size; (void)ws_size;
  const float* x    = (const float*)d_in[0];
  const float* w_in = (const float*)d_in[1];
  const float* b_in = (const float*)d_in[2];
  const float* w_op = (const float*)d_in[3];
  const float* b_op = (const float*)d_in[4];
  const float* g1   = (const float*)d_in[5];
  const float* b1   = (const float*)d_in[6];
  const float* g2   = (const float*)d_in[7];
  const float* b2v  = (const float*)d_in[8];
  const float* wfc  = (const float*)d_in[9];
  const float* bfc  = (const float*)d_in[10];

  float* out_x = (float*)d_out;
  float* out_w = out_x + (size_t)MROWS*D_MODEL;

  char* ws = (char*)d_ws;
  u16* qkv  = (u16*)ws;                                                 // 16448*2304*2 B
  u16* hbuf = (u16*)(ws + (size_t)MROWS*2304*2);                        // h then attn, 16448*768*2 B
  u16* x2b  = (u16*)(ws + (size_t)MROWS*2304*2 + (size_t)MROWS*768*2);  // x2 bf16

  dim3 blk(256);
  // LN1: x (fp32) -> h (bf16)
  ln_kernel<float><<<dim3(MROWS/4), blk, 0, stream>>>(x, g1, b1, hbuf, MROWS);
  // QKV: h @ in_proj_w^T + b
  gemm_bt<0><<<dim3(129,18), blk, 0, stream>>>(hbuf, w_in, b_in, qkv, nullptr, MROWS, 2304, 768);
  // attention: qkv -> weights (d_out tail, fp32) + attn (hbuf, bf16)
  attn_kernel<<<dim3(768,5), blk, 0, stream>>>(qkv, out_w, hbuf);
  // out_proj + residual(x fp32) -> x2 (bf16)
  gemm_bt<1><<<dim3(129,6), blk, 0, stream>>>(hbuf, w_op, b_op, x2b, x, MROWS, 768, 768);
  // LN2: x2 (bf16) -> h2 (bf16, reuse qkv buffer)
  ln_kernel<u16><<<dim3(MROWS/4), blk, 0, stream>>>(x2b, g2, b2v, qkv, MROWS);
  // fc + quickgelu + residual(x2 bf16) -> out_x (fp32)
  gemm_bt<2><<<dim3(129,6), blk, 0, stream>>>(qkv, wfc, bfc, out_x, x2b, MROWS, 768, 768);
}